// Round 3
// baseline (68.129 us; speedup 1.0000x reference)
//
#include <hip/hip_runtime.h>

// PUMA crossbar conv reduced to exact integer conv (ADC stage is identity:
// max analog column sum 128*3=384 < 2^9-1=511, all integers exact in fp32).
// acc[p,c] = sum_l s16(rne(x*2^12)) * rne(w*2^12); out = clip(rne(acc/2^12))/2^12.
// Single fused kernel: block = 16 px (one ow-row) x 32 couts; w-slice and
// im2col'd x quantized into LDS per block; v_dot2_i32_i16 inner product.

#define CIN 64
#define COUT 128
#define HW 16
#define LDIM 576           // 64*3*3
#define LP 288             // packed s16-pair dwords per patch
#define QS 4096.0f
#define CC 32              // couts per block
#define PXT 16             // pixels per block (full ow row: same b, oh)

typedef short short2v __attribute__((ext_vector_type(2)));

__device__ inline int dot2(int a, int b, int c) {
#if __has_builtin(__builtin_amdgcn_sdot2)
    union { int i; short2v v; } ua, ub;
    ua.i = a; ub.i = b;
    return __builtin_amdgcn_sdot2(ua.v, ub.v, c, false);
#else
    return c + (int)(short)(a & 0xFFFF) * (int)(short)(b & 0xFFFF)
             + (a >> 16) * (b >> 16);
#endif
}

__device__ inline int pack16(int s0, int s1) {
    return (int)(((unsigned)(unsigned short)(short)s1 << 16) |
                 (unsigned short)(short)s0);
}

__global__ __launch_bounds__(256) void fused_conv_kernel(const float* __restrict__ x,
                                                         const float* __restrict__ w,
                                                         float* __restrict__ out) {
    __shared__ int ws2[144 * 64];      // [lp2][cc][2] : 36 KB, packed w slice
    __shared__ int xs[PXT][LP];        // [px][lp]     : 18 KB, packed patches

    const int tid = threadIdx.x;
    const int ctile = blockIdx.x & 3;
    const int pxtile = blockIdx.x >> 2;
    const int c0 = ctile * CC;
    const int b  = pxtile >> 4;
    const int oh = pxtile & 15;

    // ---- stage w slice: 32 rows x 576 floats -> quantize -> packed LDS ----
    {
        const int cc = tid & 31, kb = tid >> 5;          // lane = cout (LDS-write friendly)
        const float4* w4 = (const float4*)w;             // rows are 2304B, 16B aligned
        #pragma unroll
        for (int k = 0; k < 18; ++k) {
            int lp2 = kb + k * 8;                        // 0..143
            float4 wv = w4[(c0 + cc) * 144 + lp2];
            int i0 = (int)rintf(wv.x * QS);              // rne(w*2^12) == pos-neg split
            int i1 = (int)rintf(wv.y * QS);
            int i2 = (int)rintf(wv.z * QS);
            int i3 = (int)rintf(wv.w * QS);
            ((int2*)ws2)[lp2 * 32 + cc] = make_int2(pack16(i0, i1), pack16(i2, i3));
        }
    }

    // ---- stage x: im2col 16 patches, quantize to s16 (two's-c wrap), pack ----
    {
        const int px = tid >> 4;                         // = ow
        const int j  = tid & 15;
        #pragma unroll 2
        for (int t = 0; t < 18; ++t) {
            int lp = j * 18 + t;
            int s[2];
            #pragma unroll
            for (int u = 0; u < 2; ++u) {
                int l = lp * 2 + u;
                int cin = l / 9, r = l - cin * 9, ki = r / 3, kj = r - ki * 3;
                int ih = oh - 1 + ki, iw = px - 1 + kj;
                float v = 0.0f;
                if ((unsigned)ih < HW && (unsigned)iw < HW)
                    v = x[((b * CIN + cin) * HW + ih) * HW + iw];
                s[u] = (int)rintf(v * QS);               // RNE, exact
            }
            xs[px][lp] = pack16(s[0], s[1]);
        }
    }
    __syncthreads();

    // ---- compute: thread = 1 cout x 2 px ----
    const int c  = tid & 31;
    const int pp = tid >> 5;                             // half-wave-uniform px pair
    const int4* xA = (const int4*)xs[2 * pp];            // broadcast b128 reads
    const int4* xB = (const int4*)xs[2 * pp + 1];
    const int2* wp = (const int2*)ws2;
    int acc0 = 0, acc1 = 0;
    #pragma unroll 8
    for (int q = 0; q < 72; ++q) {
        int4 xa = xA[q], xb = xB[q];                     // lp = 4q..4q+3
        int2 wA = wp[(2 * q) * 32 + c];                  // lp 4q, 4q+1 (conflict-free b64)
        int2 wB = wp[(2 * q + 1) * 32 + c];              // lp 4q+2, 4q+3
        acc0 = dot2(xa.x, wA.x, dot2(xa.y, wA.y, dot2(xa.z, wB.x, dot2(xa.w, wB.y, acc0))));
        acc1 = dot2(xb.x, wA.x, dot2(xb.y, wA.y, dot2(xb.z, wB.x, dot2(xb.w, wB.y, acc1))));
    }

    // ---- accumulator fixed-point quantize: RNE(acc/4096), clip s16, /4096 ----
    int accs[2] = {acc0, acc1};
    float o[2];
    #pragma unroll
    for (int jj = 0; jj < 2; ++jj) {
        int a = accs[jj];
        int f = a >> 12, r = a & 4095;
        int q = f + ((r > 2048) || (r == 2048 && (f & 1)));
        q = min(max(q, -32768), 32767);
        o[jj] = (float)q * (1.0f / QS);
    }
    float2* o2 = (float2*)&out[(((b * COUT + c0 + c) * HW + oh) * HW) + 2 * pp];
    *o2 = make_float2(o[0], o[1]);
}

extern "C" void kernel_launch(void* const* d_in, const int* in_sizes, int n_in,
                              void* d_out, int out_size, void* d_ws, size_t ws_size,
                              hipStream_t stream) {
    const float* x = (const float*)d_in[0];   // [4,64,16,16]
    const float* w = (const float*)d_in[1];   // [128,64,3,3]
    float* out = (float*)d_out;               // [4,128,16,16]
    fused_conv_kernel<<<256, 256, 0, stream>>>(x, w, out);
}

// Round 4
// 63.986 us; speedup vs baseline: 1.0647x; 1.0647x over previous
//
#include <hip/hip_runtime.h>

// PUMA crossbar conv reduced to exact integer conv (ADC stage is identity:
// max analog column sum 128*3=384 < 2^9-1=511, all integers exact in fp32).
// acc[p,c] = sum_l s16(rne(x*2^12)) * rne(w*2^12); out = clip(rne(acc/2^12))/2^12.
// Reduction reordered cin-major (exact i32 sum, order-free): pack s16 pairs
// along cin, dot2 inner product. Single kernel: block = 64 px x 4 couts,
// wave = one cout (w reads wave-uniform broadcast), grid 512 = 2 blocks/CU.

#define CIN 64
#define COUT 128
#define HW 16
#define QS 4096.0f

typedef short short2v __attribute__((ext_vector_type(2)));

__device__ inline int dot2(int a, int b, int c) {
#if __has_builtin(__builtin_amdgcn_sdot2)
    union { int i; short2v v; } ua, ub;
    ua.i = a; ub.i = b;
    return __builtin_amdgcn_sdot2(ua.v, ub.v, c, false);
#else
    return c + (int)(short)(a & 0xFFFF) * (int)(short)(b & 0xFFFF)
             + (a >> 16) * (b >> 16);
#endif
}

__device__ inline int pack16(int s0, int s1) {
    return (int)(((unsigned)(unsigned short)(short)s1 << 16) |
                 (unsigned short)(short)s0);
}

__global__ __launch_bounds__(256) void fused_conv_kernel(const float* __restrict__ x,
                                                         const float* __restrict__ w,
                                                         float* __restrict__ out) {
    // xs: [pos = ih6*18 + iws][cin2] dwords; 16B chunks XOR-swizzled by pos&7
    // so compute-phase b128 reads (64 lanes, distinct pos) hit all 32 banks.
    __shared__ int   xs[108 * 32];            // 13824 B
    __shared__ short wsh[4][9][64];           // [cc][ki*3+kj][cin], 4608 B

    const int tid = threadIdx.x;
    const int ct = blockIdx.x & 31;           // 32 c-tiles x 4 couts
    const int pt = blockIdx.x >> 5;           // 16 px-tiles x 64 px
    const int c0 = ct * 4;
    const int b  = pt >> 2;
    const int oh0 = (pt & 3) * 4;

    // ---- stage w: 4 rows x 144 float4 (coalesced), quantize, s16 scatter ----
    for (int i = tid; i < 576; i += 256) {
        int cc = i / 144, q = i - cc * 144;
        float4 wv = ((const float4*)w)[(c0 + cc) * 144 + q];
        float f[4] = {wv.x, wv.y, wv.z, wv.w};
        #pragma unroll
        for (int u = 0; u < 4; ++u) {
            int lu = q * 4 + u;                 // l = cin*9 + (ki*3+kj)
            int cin = lu / 9, kk = lu - cin * 9;
            wsh[cc][kk][cin] = (short)(int)rintf(f[u] * QS);  // rne(w*2^12)
        }
    }

    // ---- stage x: im2col rows oh0-1..oh0+4, width -1..16, quantize+pack ----
    for (int i = tid; i < 3456; i += 256) {    // 108 pos x 32 cin2, lanes run along pos
        int cin2 = i / 108, pos = i - cin2 * 108;
        int ih6 = pos / 18, iws = pos - ih6 * 18;
        int ih = oh0 - 1 + ih6, iw = iws - 1;
        int s0 = 0, s1 = 0;
        if ((unsigned)ih < HW && (unsigned)iw < HW) {
            const float* xp = &x[((b * CIN + 2 * cin2) * HW + ih) * HW + iw];
            s0 = (int)rintf(xp[0] * QS);        // RNE, exact; s16 wrap in pack
            s1 = (int)rintf(xp[HW * HW] * QS);
        }
        int ch = cin2 >> 2;
        xs[pos * 32 + ((ch ^ (pos & 7)) << 2) + (cin2 & 3)] = pack16(s0, s1);
    }
    __syncthreads();

    // ---- compute: wave = one cout; lane = one pixel (4 oh-rows x 16 ow) ----
    const int cc   = tid >> 6;
    const int lane = tid & 63;
    const int ohr  = lane >> 4, ow = lane & 15;
    int acc0 = 0, acc1 = 0, acc2 = 0, acc3 = 0;   // 4 chains for VALU ILP
    #pragma unroll
    for (int ki = 0; ki < 3; ++ki) {
        #pragma unroll
        for (int kj = 0; kj < 3; ++kj) {
            int pos  = (ohr + ki) * 18 + ow + kj;   // stored row = ohr+ki, col = ow+kj
            int base = pos * 32, p7 = pos & 7;
            const int4* wrow = (const int4*)&wsh[cc][ki * 3 + kj][0];
            #pragma unroll
            for (int ch = 0; ch < 8; ++ch) {
                int4 xa = *(const int4*)&xs[base + ((ch ^ p7) << 2)];  // cin 8ch..8ch+7
                int4 wa = wrow[ch];                  // wave-uniform broadcast
                acc0 = dot2(xa.x, wa.x, acc0);
                acc1 = dot2(xa.y, wa.y, acc1);
                acc2 = dot2(xa.z, wa.z, acc2);
                acc3 = dot2(xa.w, wa.w, acc3);
            }
        }
    }

    // ---- accumulator fixed-point quantize: RNE(acc/4096), clip s16, /4096 ----
    int a = acc0 + acc1 + acc2 + acc3;
    int fl = a >> 12, r = a & 4095;
    int q = fl + ((r > 2048) || (r == 2048 && (fl & 1)));
    q = min(max(q, -32768), 32767);
    out[((b * COUT + c0 + cc) * HW + oh0 + ohr) * HW + ow] = (float)q * (1.0f / QS);
}

extern "C" void kernel_launch(void* const* d_in, const int* in_sizes, int n_in,
                              void* d_out, int out_size, void* d_ws, size_t ws_size,
                              hipStream_t stream) {
    const float* x = (const float*)d_in[0];   // [4,64,16,16]
    const float* w = (const float*)d_in[1];   // [128,64,3,3]
    float* out = (float*)d_out;               // [4,128,16,16]
    fused_conv_kernel<<<512, 256, 0, stream>>>(x, w, out);
}